// Round 10
// baseline (115.062 us; speedup 1.0000x reference)
//
#include <hip/hip_runtime.h>
#include <hip/hip_bf16.h>
#include <math.h>

// ---------------------------------------------------------------------------
// GraphBased_selfAttnLayer — collapsed attention path, 6 launches.
//
//   G_v  = (S_{v-1} K)^T V            (MFMA, K-dim 8192, VT-layout, LDS-staged)
//   M_u  = scale * sum_v cw[u][v] G_v
//   attn = sum_u S_{u-1}(Q M_u) + cb*colsum(V); h = x + LN1(attn); l2 = LN2(h)
//   z = l2@m1w^T; BN; out = h + relu@m2w^T
//
// Launches: qkv -> g -> combine -> attn+LN (in-reg LN) -> z -> out.
//
// ws (bytes):
//   QbG bf16 [8194][256]   @ 0
//   KT  bf16 [256][8192]   @  4,195,328
//   VT  bf16 [256][8200]   @  8,389,632   (guard cols 0/8193; VT[j][c]=V[c-1][j])
//   GP  f32 [48][256][256] @ 12,588,032   <- after combine: L2 (8.39MB) + Z (4.19MB)
//   MT  bf16 [3][256][256] @ 25,170,944
//   SVP f32 [256][256]     @ 25,564,160
//   SVC f32 [256]          @ 25,826,304
//   RED f32 [512]          @ 25,827,328
//   ZSP f32 [256][256]     @ 25,829,376   (ends 26,091,520)
// NOTE: L2/Z intentionally NOT aliased over QbG (attn_ln reads QbG while
// writing l2 -> would race across blocks).
// ---------------------------------------------------------------------------

#define N_ 8192
#define D_ 256
#define H_ 128
#define EPSF 1e-5f

typedef unsigned short ushort_t;
typedef unsigned int uint_t;
typedef __attribute__((ext_vector_type(8))) short bf16x8;
typedef __attribute__((ext_vector_type(4))) short bf16x4;
typedef __attribute__((ext_vector_type(4))) float f32x4;

static const size_t OFF_QB  = 0;
static const size_t OFF_KT  = 4195328;
static const size_t OFF_VT  = 8389632;
static const size_t OFF_GP  = 12588032;
static const size_t OFF_MT  = 25170944;
static const size_t OFF_SVP = 25564160;
static const size_t OFF_SVC = 25826304;
static const size_t OFF_RED = 25827328;
static const size_t OFF_ZSP = 25829376;
static const size_t WS_NEED = 26091520;

#define VT_S 8200   // VT row stride (elems)

__device__ __forceinline__ ushort_t f2bf(float f) {
    __hip_bfloat16 h = __float2bfloat16(f);
    return reinterpret_cast<ushort_t&>(h);
}

__device__ __forceinline__ bf16x8 cvt8(float4 f0, float4 f1) {
    bf16x8 o;
    o[0] = (short)f2bf(f0.x); o[1] = (short)f2bf(f0.y);
    o[2] = (short)f2bf(f0.z); o[3] = (short)f2bf(f0.w);
    o[4] = (short)f2bf(f1.x); o[5] = (short)f2bf(f1.y);
    o[6] = (short)f2bf(f1.z); o[7] = (short)f2bf(f1.w);
    return o;
}

// ---------------------------------------------------------------------------
// qkv via MFMA with LDS-staged operands (unchanged from round 9, proven).
// ---------------------------------------------------------------------------
__global__ void __launch_bounds__(256)
qkv_mfma(const float* __restrict__ x,
         const float* __restrict__ wq, const float* __restrict__ bq,
         const float* __restrict__ wk, const float* __restrict__ bk,
         const float* __restrict__ wv, const float* __restrict__ bv,
         ushort_t* __restrict__ QbG, ushort_t* __restrict__ KT,
         ushort_t* __restrict__ VT,
         float* __restrict__ RED, float* __restrict__ SVP)
{
    __shared__ ushort_t XS[32][264];
    __shared__ ushort_t WS[256][40];
    __shared__ float lds4[4];
    const int tid = threadIdx.x, lane = tid & 63, wid = tid >> 6;
    const int sel = blockIdx.y;
    const int i0 = blockIdx.x * 32;
    const int jw = wid * 64;
    const int l15 = lane & 15, kg = lane >> 4;
    const float* W = (sel == 0) ? wq : ((sel == 1) ? wk : wv);
    const float* B = (sel == 0) ? bq : ((sel == 1) ? bk : bv);

    if (sel == 0 && blockIdx.x == 0) {
        QbG[tid] = 0; QbG[(size_t)8193 * 256 + tid] = 0;
        VT[(size_t)tid * VT_S] = 0; VT[(size_t)tid * VT_S + 8193] = 0;
    }

#pragma unroll
    for (int p = 0; p < 4; ++p) {
        int lin = p * 256 + tid;
        int row = lin >> 5;
        int c8  = (lin & 31) * 8;
        const float* xp = x + (size_t)(i0 + row) * 256 + c8;
        *(bf16x8*)(&XS[row][c8]) = cvt8(*(const float4*)xp, *(const float4*)(xp + 4));
    }

    f32x4 acc[2][4];
#pragma unroll
    for (int mi = 0; mi < 2; ++mi)
#pragma unroll
        for (int ni = 0; ni < 4; ++ni) acc[mi][ni] = 0.0f;

    for (int k0 = 0; k0 < 256; k0 += 32) {
        __syncthreads();
#pragma unroll
        for (int p = 0; p < 4; ++p) {
            int j  = p * 64 + (tid >> 2);
            int c8 = (tid & 3) * 8;
            const float* wp = W + (size_t)j * 256 + k0 + c8;
            *(bf16x8*)(&WS[j][c8]) = cvt8(*(const float4*)wp, *(const float4*)(wp + 4));
        }
        __syncthreads();

        bf16x8 a[2], b[4];
#pragma unroll
        for (int mi = 0; mi < 2; ++mi)
            a[mi] = *(const bf16x8*)(&XS[16 * mi + l15][k0 + 8 * kg]);
#pragma unroll
        for (int ni = 0; ni < 4; ++ni)
            b[ni] = *(const bf16x8*)(&WS[jw + 16 * ni + l15][8 * kg]);
#pragma unroll
        for (int mi = 0; mi < 2; ++mi)
#pragma unroll
            for (int ni = 0; ni < 4; ++ni)
                acc[mi][ni] = __builtin_amdgcn_mfma_f32_16x16x32_bf16(a[mi], b[ni], acc[mi][ni], 0, 0, 0);
    }

    float ssq = 0.0f;
    float colp[4] = {0.0f, 0.0f, 0.0f, 0.0f};

    if (sel == 0) {
#pragma unroll
        for (int mi = 0; mi < 2; ++mi)
#pragma unroll
            for (int ni = 0; ni < 4; ++ni) {
                const int col = jw + 16 * ni + l15;
                const float bias = B[col];
#pragma unroll
                for (int r = 0; r < 4; ++r) {
                    const int row = i0 + 16 * mi + 4 * kg + r;
                    float val = acc[mi][ni][r] + bias;
                    QbG[(size_t)(row + 1) * 256 + col] = f2bf(val);
                    ssq = fmaf(val, val, ssq);
                }
            }
    } else if (sel == 1) {
#pragma unroll
        for (int mi = 0; mi < 2; ++mi)
#pragma unroll
            for (int ni = 0; ni < 4; ++ni) {
                const int col = jw + 16 * ni + l15;   // d
                const float bias = B[col];
                const int tb = i0 + 16 * mi + 4 * kg;
                bf16x4 pk;
#pragma unroll
                for (int r = 0; r < 4; ++r) {
                    float val = acc[mi][ni][r] + bias;
                    ssq = fmaf(val, val, ssq);
                    pk[r] = (short)f2bf(val);
                }
                *(bf16x4*)(KT + (size_t)col * 8192 + tb) = pk;
            }
    } else {
#pragma unroll
        for (int mi = 0; mi < 2; ++mi)
#pragma unroll
            for (int ni = 0; ni < 4; ++ni) {
                const int col = jw + 16 * ni + l15;   // j
                const float bias = B[col];
                const int tb = i0 + 16 * mi + 4 * kg;
                float v0 = acc[mi][ni][0] + bias, v1 = acc[mi][ni][1] + bias;
                float v2 = acc[mi][ni][2] + bias, v3 = acc[mi][ni][3] + bias;
                colp[ni] += v0 + v1 + v2 + v3;
                ushort_t* p = VT + (size_t)col * VT_S + tb + 1;
                p[0] = f2bf(v0);
                *(uint_t*)(p + 1) = (uint_t)f2bf(v1) | ((uint_t)f2bf(v2) << 16);
                p[3] = f2bf(v3);
            }
    }

    if (sel < 2) {
        float s = ssq;
#pragma unroll
        for (int o = 32; o > 0; o >>= 1) s += __shfl_down(s, o);
        if (lane == 0) lds4[wid] = s;
        __syncthreads();
        if (tid == 0)
            RED[sel * 256 + blockIdx.x] = lds4[0] + lds4[1] + lds4[2] + lds4[3];
    } else {
#pragma unroll
        for (int ni = 0; ni < 4; ++ni) {
            float v = colp[ni];
            v += __shfl_xor(v, 16);
            v += __shfl_xor(v, 32);
            if (kg == 0)
                SVP[(size_t)blockIdx.x * 256 + jw + 16 * ni + l15] = v;
        }
    }
}

// ---------------------------------------------------------------------------
// G_v[d][j] = sum_t K[t][d] * V[t+1-v][j].  grid (4, 4, 16) = 256 blocks.
// LDS-staged: KS[64][40] (32 t), VS[64][40] (40 t incl. shift halo).
// v=2 frag = b128; v=0 = splice(b128, +b32); v=1 = alignbit of both.
// ---------------------------------------------------------------------------
__global__ void __launch_bounds__(256)
g_mfma(const ushort_t* __restrict__ KT, const ushort_t* __restrict__ VT,
       float* __restrict__ GP)
{
    __shared__ ushort_t KS[64][40];
    __shared__ ushort_t VS[64][40];
    const int tid = threadIdx.x, lane = tid & 63, wid = tid >> 6;
    const int d0 = blockIdx.x * 64;
    const int jb = blockIdx.y * 64;
    const int wrow = wid * 16;
    const int ks = blockIdx.z;
    const int l15 = lane & 15, kg = lane >> 4;

    f32x4 acc[3][4];
#pragma unroll
    for (int v = 0; v < 3; ++v)
#pragma unroll
        for (int mi = 0; mi < 4; ++mi) acc[v][mi] = 0.0f;

    for (int tt = 0; tt < 512; tt += 32) {
        const int t0 = ks * 512 + tt;
        __syncthreads();
        // stage KS: 64 rows x 32 t (1 pass)
        {
            int row = tid >> 2, u = tid & 3;
            *(bf16x8*)(&KS[row][u * 8]) =
                *(const bf16x8*)(KT + (size_t)(d0 + row) * 8192 + t0 + u * 8);
        }
        // stage VS: 64 rows x 40 t (2 passes, 320 units)
#pragma unroll
        for (int p = 0; p < 2; ++p) {
            int idx = p * 256 + tid;
            if (idx < 320) {
                int row = idx / 5, u = idx % 5;
                *(bf16x8*)(&VS[row][u * 8]) =
                    *(const bf16x8*)(VT + (size_t)(jb + row) * VT_S + t0 + u * 8);
            }
        }
        __syncthreads();

        bf16x8 a[4];
#pragma unroll
        for (int mi = 0; mi < 4; ++mi)
            a[mi] = *(const bf16x8*)(&KS[16 * mi + l15][8 * kg]);

        uint4 r0 = *(const uint4*)(&VS[wrow + l15][8 * kg]);      // e0..7 (v=2)
        uint_t ex = *(const uint_t*)(&VS[wrow + l15][8 * kg + 8]); // e8,e9
        uint4 r2;                                                  // e2..9 (v=0)
        r2.x = r0.y; r2.y = r0.z; r2.z = r0.w; r2.w = ex;
        uint4 m1;                                                  // e1..8 (v=1)
        m1.x = (r0.x >> 16) | (r2.x << 16);
        m1.y = (r0.y >> 16) | (r2.y << 16);
        m1.z = (r0.z >> 16) | (r2.z << 16);
        m1.w = (r0.w >> 16) | (r2.w << 16);
        bf16x8 b2 = __builtin_bit_cast(bf16x8, r0);
        bf16x8 b0 = __builtin_bit_cast(bf16x8, r2);
        bf16x8 b1 = __builtin_bit_cast(bf16x8, m1);
#pragma unroll
        for (int mi = 0; mi < 4; ++mi) {
            acc[0][mi] = __builtin_amdgcn_mfma_f32_16x16x32_bf16(a[mi], b0, acc[0][mi], 0, 0, 0);
            acc[1][mi] = __builtin_amdgcn_mfma_f32_16x16x32_bf16(a[mi], b1, acc[1][mi], 0, 0, 0);
            acc[2][mi] = __builtin_amdgcn_mfma_f32_16x16x32_bf16(a[mi], b2, acc[2][mi], 0, 0, 0);
        }
    }

#pragma unroll
    for (int v = 0; v < 3; ++v) {
        float* gp = GP + (size_t)(ks * 3 + v) * 65536;
#pragma unroll
        for (int mi = 0; mi < 4; ++mi)
#pragma unroll
            for (int r = 0; r < 4; ++r)
                gp[(size_t)(d0 + 16 * mi + 4 * kg + r) * 256 + (jb + wrow + l15)]
                    = acc[v][mi][r];
    }
}

// ---------------------------------------------------------------------------
// MT[u][j][d] = scale * sum_v cw[u][v] * sum_ks GP[ks*3+v][d][j]  (bf16).
// scale via parallel 256-thread reduction; block 0 computes SVC.
// ---------------------------------------------------------------------------
__global__ void combine_m(const float* __restrict__ GP, const float* __restrict__ cw,
                          const float* __restrict__ RED, const float* __restrict__ SVP,
                          const float* __restrict__ cb,
                          ushort_t* __restrict__ MT, float* __restrict__ SVC)
{
    __shared__ float lds8[8];
    __shared__ float scsh;
    const int d = blockIdx.x, j = threadIdx.x;

    float sq = RED[j], sk = RED[256 + j];
#pragma unroll
    for (int o = 32; o > 0; o >>= 1) { sq += __shfl_down(sq, o); sk += __shfl_down(sk, o); }
    if ((j & 63) == 0) { lds8[j >> 6] = sq; lds8[4 + (j >> 6)] = sk; }

    float g[3] = {0.0f, 0.0f, 0.0f};
    for (int ks = 0; ks < 16; ++ks)
#pragma unroll
        for (int v = 0; v < 3; ++v)
            g[v] += GP[(size_t)(ks * 3 + v) * 65536 + (size_t)d * 256 + j];

    __syncthreads();
    if (j == 0) {
        float SQ = lds8[0] + lds8[1] + lds8[2] + lds8[3];
        float SK = lds8[4] + lds8[5] + lds8[6] + lds8[7];
        scsh = rsqrtf(SQ) * rsqrtf(SK);
    }
    __syncthreads();
    const float sc = scsh;

#pragma unroll
    for (int u = 0; u < 3; ++u) {
        float m = sc * (cw[u * 3 + 0] * g[0] + cw[u * 3 + 1] * g[1] + cw[u * 3 + 2] * g[2]);
        MT[(size_t)u * 65536 + (size_t)j * 256 + d] = f2bf(m);
    }
    if (d == 0) {
        float s = 0.0f;
        for (int b = 0; b < 256; ++b) s += SVP[(size_t)b * 256 + j];
        SVC[j] = cb[0] * s;
    }
}

// ---------------------------------------------------------------------------
// attn + LN fully fused, in-register. grid 256: 32 rows x 256 cols,
// 4 waves each 64 cols. Row stats (sum, sumsq) via shfl + tiny LDS
// cross-wave reduce; LN applied in regs; h -> d_out, l2 -> L2 buf.
// ---------------------------------------------------------------------------
__global__ void __launch_bounds__(256)
attn_ln_mfma(const ushort_t* __restrict__ QbG, const ushort_t* __restrict__ MT,
             const float* __restrict__ SVC, const float* __restrict__ x,
             const float* __restrict__ ln1g, const float* __restrict__ ln1b,
             const float* __restrict__ ln2g, const float* __restrict__ ln2b,
             float* __restrict__ h, float* __restrict__ l2)
{
    __shared__ float redS[32][4];
    __shared__ float redQ[32][4];
    __shared__ float rowM[32], rowR[32];
    const int tid = threadIdx.x, lane = tid & 63, wid = tid >> 6;
    const int i0 = blockIdx.x * 32;
    const int jw = wid * 64;
    const int l15 = lane & 15, kg = lane >> 4;

    float acc[2][4][4];
    {
        f32x4 accv[2][4];
#pragma unroll
        for (int mi = 0; mi < 2; ++mi)
#pragma unroll
            for (int ni = 0; ni < 4; ++ni) accv[mi][ni] = 0.0f;

        for (int k0 = 0; k0 < 256; k0 += 32) {
            bf16x8 a[3][2], b[3][4];
#pragma unroll
            for (int u = 0; u < 3; ++u)
#pragma unroll
                for (int mi = 0; mi < 2; ++mi)
                    a[u][mi] = *(const bf16x8*)(QbG
                        + (size_t)(i0 + 16 * mi + l15 + u) * 256 + k0 + 8 * kg);
#pragma unroll
            for (int u = 0; u < 3; ++u)
#pragma unroll
                for (int ni = 0; ni < 4; ++ni)
                    b[u][ni] = *(const bf16x8*)(MT + (size_t)u * 65536
                        + (size_t)(jw + 16 * ni + l15) * 256 + k0 + 8 * kg);
#pragma unroll
            for (int mi = 0; mi < 2; ++mi)
#pragma unroll
                for (int ni = 0; ni < 4; ++ni)
#pragma unroll
                    for (int u = 0; u < 3; ++u)
                        accv[mi][ni] = __builtin_amdgcn_mfma_f32_16x16x32_bf16(
                            a[u][mi], b[u][ni], accv[mi][ni], 0, 0, 0);
        }
        // add SVC, move to scalar array
#pragma unroll
        for (int ni = 0; ni < 4; ++ni) {
            const float sv = SVC[jw + 16 * ni + l15];
#pragma unroll
            for (int mi = 0; mi < 2; ++mi)
#pragma unroll
                for (int r = 0; r < 4; ++r)
                    acc[mi][ni][r] = accv[mi][ni][r] + sv;
        }
    }

    // ---- LN1 stats: per-row sum / sumsq over this wave's 64 cols ----
#pragma unroll
    for (int mi = 0; mi < 2; ++mi)
#pragma unroll
        for (int r = 0; r < 4; ++r) {
            float s = acc[mi][0][r] + acc[mi][1][r] + acc[mi][2][r] + acc[mi][3][r];
            float q = acc[mi][0][r] * acc[mi][0][r];
            q = fmaf(acc[mi][1][r], acc[mi][1][r], q);
            q = fmaf(acc[mi][2][r], acc[mi][2][r], q);
            q = fmaf(acc[mi][3][r], acc[mi][3][r], q);
#pragma unroll
            for (int o = 1; o < 16; o <<= 1) { s += __shfl_xor(s, o); q += __shfl_xor(q, o); }
            if (l15 == 0) {
                redS[16 * mi + 4 * kg + r][wid] = s;
                redQ[16 * mi + 4 * kg + r][wid] = q;
            }
        }
    __syncthreads();
    if (tid < 32) {
        float S = redS[tid][0] + redS[tid][1] + redS[tid][2] + redS[tid][3];
        float Q = redQ[tid][0] + redQ[tid][1] + redQ[tid][2] + redQ[tid][3];
        float m = S * (1.0f / D_);
        float var = Q * (1.0f / D_) - m * m;
        rowM[tid] = m;
        rowR[tid] = rsqrtf(var + EPSF);
    }
    __syncthreads();

    // ---- apply LN1 + residual; keep h in regs ----
    float g1[4], b1[4], g2[4], b2[4];
#pragma unroll
    for (int ni = 0; ni < 4; ++ni) {
        const int col = jw + 16 * ni + l15;
        g1[ni] = ln1g[col]; b1[ni] = ln1b[col];
        g2[ni] = ln2g[col]; b2[ni] = ln2b[col];
    }
    float hv[2][4][4];
#pragma unroll
    for (int mi = 0; mi < 2; ++mi)
#pragma unroll
        for (int r = 0; r < 4; ++r) {
            const int R = 16 * mi + 4 * kg + r;
            const float m = rowM[R], rs = rowR[R];
#pragma unroll
            for (int ni = 0; ni < 4; ++ni) {
                const int col = jw + 16 * ni + l15;
                const size_t off = (size_t)(i0 + R) * 256 + col;
                float d = acc[mi][ni][r] - m;
                float hh = x[off] + d * rs * g1[ni] + b1[ni];
                hv[mi][ni][r] = hh;
                h[off] = hh;
            }
        }
    __syncthreads();   // LN1 stat reads done; safe to reuse redS/redQ

    // ---- LN2 stats on hv ----
#pragma unroll
    for (int mi = 0; mi < 2; ++mi)
#pragma unroll
        for (int r = 0; r < 4; ++r) {
            float s = hv[mi][0][r] + hv[mi][1][r] + hv[mi][2][r] + hv[mi][3][r];
            float q = hv[mi][0][r] * hv[mi][0][r];
            q = fmaf(hv[mi][1][r], hv[mi][1][r], q);
            q = fmaf(hv[mi][2][r], hv[mi][2][r], q);
            q = fmaf(hv[mi][3][r], hv[mi][3][r], q);
#pragma unroll
            for (int o = 1; o < 16; o <<= 1) { s += __shfl_xor(s, o); q += __shfl_xor(q, o); }
            if (l15 == 0) {
                redS[16 * mi + 4 * kg + r][wid] = s;
                redQ[16 * mi + 4 * kg + r][wid] = q;
            }
        }
    __syncthreads();
    if (tid < 32) {
        float S = redS[tid][0] + redS[tid][1] + redS[tid][2] + redS[tid][3];
        float Q = redQ[tid][0] + redQ[tid][1] + redQ[tid][2] + redQ[tid][3];
        float m = S * (1.0f / D_);
        float var = Q * (1.0f / D_) - m * m;
        rowM[tid] = m;
        rowR[tid] = rsqrtf(var + EPSF);
    }
    __syncthreads();

    // ---- apply LN2 -> l2 ----
#pragma unroll
    for (int mi = 0; mi < 2; ++mi)
#pragma unroll
        for (int r = 0; r < 4; ++r) {
            const int R = 16 * mi + 4 * kg + r;
            const float m2 = rowM[R], rs2 = rowR[R];
#pragma unroll
            for (int ni = 0; ni < 4; ++ni) {
                const int col = jw + 16 * ni + l15;
                const size_t off = (size_t)(i0 + R) * 256 + col;
                l2[off] = (hv[mi][ni][r] - m2) * rs2 * g2[ni] + b2[ni];
            }
        }
}

// ---------------------------------------------------------------------------
// z = l2 @ m1w^T via MFMA, LDS-staged. grid 256: 32 rows x 128 cols,
// 4 waves each 32 cols. Epilogue: z store f32 + BN partials -> ZSP.
// ---------------------------------------------------------------------------
__global__ void __launch_bounds__(256)
gemm_z_mfma(const float* __restrict__ L2, const float* __restrict__ W,
            float* __restrict__ Z, float* __restrict__ ZSP)
{
    __shared__ ushort_t XS[32][264];
    __shared__ ushort_t WS[128][40];
    const int tid = threadIdx.x, lane = tid & 63, wid = tid >> 6;
    const int i0 = blockIdx.x * 32;
    const int jw = wid * 32;
    const int l15 = lane & 15, kg = lane >> 4;

#pragma unroll
    for (int p = 0; p < 4; ++p) {
        int idx = p * 256 + tid;
        int row = idx >> 5;
        int c8  = (idx & 31) * 8;
        const float* xp = L2 + (size_t)(i0 + row) * 256 + c8;
        *(bf16x8*)(&XS[row][c8]) = cvt8(*(const float4*)xp, *(const float4*)(xp + 4));
    }

    f32x4 acc[2][2];
#pragma unroll
    for (int mi = 0; mi < 2; ++mi) { acc[mi][0] = 0.0f; acc[mi][1] = 0.0f; }

    for (int k0 = 0; k0 < 256; k0 += 32) {
        __syncthreads();
#pragma unroll
        for (int p = 0; p < 2; ++p) {
            int idx = p * 256 + tid;
            int j  = idx >> 2;
            int c8 = (idx & 3) * 8;
            const float* wp = W + (size_t)j * 256 + k0 + c8;
            *(bf16x8*)(&WS[j][c8]) = cvt8(*(const float4*)wp, *(const float4*)(wp + 4));
        }
        __syncthreads();

        bf16x8 a[2], b[2];
#pragma unroll
        for (int mi = 0; mi < 2; ++mi)
            a[mi] = *(const bf16x8*)(&XS[16 * mi + l15][k0 + 8 * kg]);
#pragma unroll
        for (int ni = 0; ni < 2; ++ni)
            b[ni] = *(const bf16x8*)(&WS[jw + 16 * ni + l15][8 * kg]);
#pragma unroll
        for (int mi = 0; mi < 2; ++mi)
#pragma unroll
            for (int ni = 0; ni < 2; ++ni)
                acc[mi][ni] = __builtin_amdgcn_mfma_f32_16x16x32_bf16(a[mi], b[ni], acc[mi][ni], 0, 0, 0);
    }

    float s[2] = {0.0f, 0.0f}, q[2] = {0.0f, 0.0f};
#pragma unroll
    for (int mi = 0; mi < 2; ++mi)
#pragma unroll
        for (int ni = 0; ni < 2; ++ni) {
            const int col = jw + 16 * ni + l15;
#pragma unroll
            for (int r = 0; r < 4; ++r) {
                float zv = acc[mi][ni][r];
                Z[(size_t)(i0 + 16 * mi + 4 * kg + r) * 128 + col] = zv;
                s[ni] += zv;
                q[ni] = fmaf(zv, zv, q[ni]);
            }
        }
#pragma unroll
    for (int ni = 0; ni < 2; ++ni) {
        s[ni] += __shfl_xor(s[ni], 16); s[ni] += __shfl_xor(s[ni], 32);
        q[ni] += __shfl_xor(q[ni], 16); q[ni] += __shfl_xor(q[ni], 32);
        if (kg == 0) {
            ZSP[(size_t)blockIdx.x * 256 + jw + 16 * ni + l15] = s[ni];
            ZSP[(size_t)blockIdx.x * 256 + 128 + jw + 16 * ni + l15] = q[ni];
        }
    }
}

// ---------------------------------------------------------------------------
// out = h + relu(z*a+b) @ m2w^T via MFMA, LDS-staged. grid 256.
// BN affine from ZSP -> LDS; affine+relu applied during XS staging.
// ---------------------------------------------------------------------------
__global__ void __launch_bounds__(256)
gemm_out_mfma(const float* __restrict__ Z, const float* __restrict__ W,
              const float* __restrict__ ZSP,
              const float* __restrict__ bng, const float* __restrict__ bnb,
              float* out)
{
    __shared__ float bnA[128], bnB[128];
    __shared__ ushort_t XS[32][136];
    __shared__ ushort_t WS[256][40];
    const int tid = threadIdx.x, lane = tid & 63, wid = tid >> 6;
    const int i0 = blockIdx.x * 32;
    const int jw = wid * 64;
    const int l15 = lane & 15, kg = lane >> 4;

    if (tid < 128) {
        float s = 0.0f, q = 0.0f;
        for (int b = 0; b < 256; ++b) {
            s += ZSP[(size_t)b * 256 + tid];
            q += ZSP[(size_t)b * 256 + 128 + tid];
        }
        float mu = s * (1.0f / N_);
        float var = q * (1.0f / N_) - mu * mu;
        float aa = rsqrtf(var + EPSF) * bng[tid];
        bnA[tid] = aa;
        bnB[tid] = bnb[tid] - mu * aa;
    }
    __syncthreads();

    // stage XS with affine+relu applied
#pragma unroll
    for (int p = 0; p < 2; ++p) {
        int idx = p * 256 + tid;
        int row = idx >> 4;
        int c8  = (idx & 15) * 8;
        const float* zp = Z + (size_t)(i0 + row) * 128 + c8;
        float4 f0 = *(const float4*)zp;
        float4 f1 = *(const float4*)(zp + 4);
        float4 g0, g1;
        g0.x = fmaxf(fmaf(f0.x, bnA[c8 + 0], bnB[c8 + 0]), 0.0f);
        g0.y = fmaxf(fmaf(f0.y, bnA[c8 + 1], bnB[c8 + 1]), 0.0f);
        g0.z = fmaxf(fmaf(f0.z, bnA[c8 + 2], bnB[c8 + 2]), 0.0f);
        g0.w = fmaxf(fmaf(f0.w, bnA[c8 + 3], bnB[c8 + 3]), 0.0f);
        g1.x = fmaxf(fmaf(f1.x, bnA[c8 + 4], bnB[c8 + 4]), 0.0f);
        g1.y = fmaxf(fmaf(f1.y, bnA[c8 + 5], bnB[c8 + 5]), 0.0f);
        g1.z = fmaxf(fmaf(f1.z, bnA[c8 + 6], bnB[c8 + 6]), 0.0f);
        g1.w = fmaxf(fmaf(f1.w, bnA[c8 + 7], bnB[c8 + 7]), 0.0f);
        *(bf16x8*)(&XS[row][c8]) = cvt8(g0, g1);
    }

    f32x4 acc[2][4];
#pragma unroll
    for (int mi = 0; mi < 2; ++mi)
#pragma unroll
        for (int ni = 0; ni < 4; ++ni) acc[mi][ni] = 0.0f;

    for (int k0 = 0; k0 < 128; k0 += 32) {
        __syncthreads();
#pragma unroll
        for (int p = 0; p < 4; ++p) {
            int idx = p * 256 + tid;
            int j  = idx >> 2;
            int c8 = (idx & 3) * 8;
            const float* wp = W + (size_t)j * 128 + k0 + c8;
            *(bf16x8*)(&WS[j][c8]) = cvt8(*(const float4*)wp, *(const float4*)(wp + 4));
        }
        __syncthreads();

        bf16x8 a[2], b[4];
#pragma unroll
        for (int mi = 0; mi < 2; ++mi)
            a[mi] = *(const bf16x8*)(&XS[16 * mi + l15][k0 + 8 * kg]);
#pragma unroll
        for (int ni = 0; ni < 4; ++ni)
            b[ni] = *(const bf16x8*)(&WS[jw + 16 * ni + l15][8 * kg]);
#pragma unroll
        for (int mi = 0; mi < 2; ++mi)
#pragma unroll
            for (int ni = 0; ni < 4; ++ni)
                acc[mi][ni] = __builtin_amdgcn_mfma_f32_16x16x32_bf16(a[mi], b[ni], acc[mi][ni], 0, 0, 0);
    }

#pragma unroll
    for (int mi = 0; mi < 2; ++mi)
#pragma unroll
        for (int ni = 0; ni < 4; ++ni)
#pragma unroll
            for (int r = 0; r < 4; ++r) {
                const size_t idx = (size_t)(i0 + 16 * mi + 4 * kg + r) * 256
                                 + (jw + 16 * ni + l15);
                out[idx] = out[idx] + acc[mi][ni][r];
            }
}

// ---------------------------------------------------------------------------
extern "C" void kernel_launch(void* const* d_in, const int* in_sizes, int n_in,
                              void* d_out, int out_size, void* d_ws, size_t ws_size,
                              hipStream_t stream)
{
    const float* x    = (const float*)d_in[0];
    const float* wq   = (const float*)d_in[1];
    const float* bq   = (const float*)d_in[2];
    const float* wk   = (const float*)d_in[3];
    const float* bk   = (const float*)d_in[4];
    const float* wv   = (const float*)d_in[5];
    const float* bv   = (const float*)d_in[6];
    const float* cw   = (const float*)d_in[7];
    const float* cb   = (const float*)d_in[8];
    const float* m1w  = (const float*)d_in[9];
    const float* m2w  = (const float*)d_in[10];
    const float* bng  = (const float*)d_in[11];
    const float* bnb  = (const float*)d_in[12];
    const float* ln1g = (const float*)d_in[13];
    const float* ln1b = (const float*)d_in[14];
    const float* ln2g = (const float*)d_in[15];
    const float* ln2b = (const float*)d_in[16];

    float* outF = (float*)d_out;
    char*  wsb  = (char*)d_ws;
    if (ws_size < WS_NEED) return;

    ushort_t* QbG = (ushort_t*)(wsb + OFF_QB);
    ushort_t* KT  = (ushort_t*)(wsb + OFF_KT);
    ushort_t* VT  = (ushort_t*)(wsb + OFF_VT);
    float*    GP  = (float*)(wsb + OFF_GP);
    ushort_t* MT  = (ushort_t*)(wsb + OFF_MT);
    float*    SVP = (float*)(wsb + OFF_SVP);
    float*    SVC = (float*)(wsb + OFF_SVC);
    float*    RED = (float*)(wsb + OFF_RED);
    float*    ZSP = (float*)(wsb + OFF_ZSP);
    // L2 and Z live in the GP region (dead after combine_m) — NOT over QbG,
    // which attn_ln still reads while writing l2.
    float*    L2  = (float*)(wsb + OFF_GP);              // 8,388,608 B
    float*    Z   = (float*)(wsb + OFF_GP + 8388608);    // 4,194,304 B

    const dim3 b256(256);

    qkv_mfma<<<dim3(256, 3), b256, 0, stream>>>(x, wq, bq, wk, bk, wv, bv,
                                                QbG, KT, VT, RED, SVP);
    g_mfma<<<dim3(4, 4, 16), b256, 0, stream>>>(KT, VT, GP);
    combine_m<<<256, b256, 0, stream>>>(GP, cw, RED, SVP, cb, MT, SVC);
    attn_ln_mfma<<<256, b256, 0, stream>>>(QbG, MT, SVC, x,
                                           ln1g, ln1b, ln2g, ln2b, outF, L2);
    gemm_z_mfma<<<256, b256, 0, stream>>>(L2, m1w, Z, ZSP);
    gemm_out_mfma<<<256, b256, 0, stream>>>(Z, m2w, ZSP, bng, bnb, outF);
}

// Round 11
// 103.502 us; speedup vs baseline: 1.1117x; 1.1117x over previous
//
#include <hip/hip_runtime.h>
#include <hip/hip_bf16.h>
#include <math.h>

// ---------------------------------------------------------------------------
// GraphBased_selfAttnLayer — collapsed attention path, 5 launches.
//
//   G_v  = (S_{v-1} K)^T V            (MFMA, K-dim 8192, VT-layout + alignbit)
//   M_u  = scale * sum_v cw[u][v] G_v
//   attn = sum_u S_{u-1}(Q M_u) + cb*colsum(V); h = x + LN1(attn);
//   l2 = LN2(h) (LDS only); z = l2@m1w^T (fused, same kernel) ; BN ;
//   out = h + relu(z*a+b) @ m2w^T
//
// Launches: qkv -> g -> combine -> attn+LN+z (fused) -> out.
// Config basis: the 105 µs round-9 kernels (qkv LDS-staged; g/out direct),
// plus parallel combine and the z-fusion. l2 never touches global memory.
//
// ws (bytes):
//   QbG bf16 [8194][256]   @ 0
//   KT  bf16 [256][8192]   @  4,195,328
//   VT  bf16 [256][8200]   @  8,389,632   (guard cols 0/8193; VT[j][c]=V[c-1][j])
//   GP  f32 [48][256][256] @ 12,588,032   <- after combine: Z f32 [8192][128]
//   MT  bf16 [3][256][256] @ 25,170,944
//   SVP f32 [256][256]     @ 25,564,160
//   SVC f32 [256]          @ 25,826,304
//   RED f32 [512]          @ 25,827,328
//   ZSP f32 [256][256]     @ 25,829,376   (ends 26,091,520)
// ---------------------------------------------------------------------------

#define N_ 8192
#define D_ 256
#define H_ 128
#define EPSF 1e-5f

typedef unsigned short ushort_t;
typedef unsigned int uint_t;
typedef __attribute__((ext_vector_type(8))) short bf16x8;
typedef __attribute__((ext_vector_type(4))) short bf16x4;
typedef __attribute__((ext_vector_type(4))) float f32x4;

static const size_t OFF_QB  = 0;
static const size_t OFF_KT  = 4195328;
static const size_t OFF_VT  = 8389632;
static const size_t OFF_GP  = 12588032;
static const size_t OFF_MT  = 25170944;
static const size_t OFF_SVP = 25564160;
static const size_t OFF_SVC = 25826304;
static const size_t OFF_RED = 25827328;
static const size_t OFF_ZSP = 25829376;
static const size_t WS_NEED = 26091520;

#define VT_S 8200   // VT row stride (elems)

__device__ __forceinline__ ushort_t f2bf(float f) {
    __hip_bfloat16 h = __float2bfloat16(f);
    return reinterpret_cast<ushort_t&>(h);
}

__device__ __forceinline__ bf16x8 cvt8(float4 f0, float4 f1) {
    bf16x8 o;
    o[0] = (short)f2bf(f0.x); o[1] = (short)f2bf(f0.y);
    o[2] = (short)f2bf(f0.z); o[3] = (short)f2bf(f0.w);
    o[4] = (short)f2bf(f1.x); o[5] = (short)f2bf(f1.y);
    o[6] = (short)f2bf(f1.z); o[7] = (short)f2bf(f1.w);
    return o;
}

__device__ __forceinline__ float waveSum(float v)
{
#pragma unroll
    for (int o = 32; o > 0; o >>= 1) v += __shfl_xor(v, o);
    return v;
}

// ---------------------------------------------------------------------------
// qkv via MFMA with LDS-staged operands (identical to the 105 µs version).
// ---------------------------------------------------------------------------
__global__ void __launch_bounds__(256)
qkv_mfma(const float* __restrict__ x,
         const float* __restrict__ wq, const float* __restrict__ bq,
         const float* __restrict__ wk, const float* __restrict__ bk,
         const float* __restrict__ wv, const float* __restrict__ bv,
         ushort_t* __restrict__ QbG, ushort_t* __restrict__ KT,
         ushort_t* __restrict__ VT,
         float* __restrict__ RED, float* __restrict__ SVP)
{
    __shared__ ushort_t XS[32][264];
    __shared__ ushort_t WS[256][40];
    __shared__ float lds4[4];
    const int tid = threadIdx.x, lane = tid & 63, wid = tid >> 6;
    const int sel = blockIdx.y;
    const int i0 = blockIdx.x * 32;
    const int jw = wid * 64;
    const int l15 = lane & 15, kg = lane >> 4;
    const float* W = (sel == 0) ? wq : ((sel == 1) ? wk : wv);
    const float* B = (sel == 0) ? bq : ((sel == 1) ? bk : bv);

    if (sel == 0 && blockIdx.x == 0) {
        QbG[tid] = 0; QbG[(size_t)8193 * 256 + tid] = 0;
        VT[(size_t)tid * VT_S] = 0; VT[(size_t)tid * VT_S + 8193] = 0;
    }

#pragma unroll
    for (int p = 0; p < 4; ++p) {
        int lin = p * 256 + tid;
        int row = lin >> 5;
        int c8  = (lin & 31) * 8;
        const float* xp = x + (size_t)(i0 + row) * 256 + c8;
        *(bf16x8*)(&XS[row][c8]) = cvt8(*(const float4*)xp, *(const float4*)(xp + 4));
    }

    f32x4 acc[2][4];
#pragma unroll
    for (int mi = 0; mi < 2; ++mi)
#pragma unroll
        for (int ni = 0; ni < 4; ++ni) acc[mi][ni] = 0.0f;

    for (int k0 = 0; k0 < 256; k0 += 32) {
        __syncthreads();
#pragma unroll
        for (int p = 0; p < 4; ++p) {
            int j  = p * 64 + (tid >> 2);
            int c8 = (tid & 3) * 8;
            const float* wp = W + (size_t)j * 256 + k0 + c8;
            *(bf16x8*)(&WS[j][c8]) = cvt8(*(const float4*)wp, *(const float4*)(wp + 4));
        }
        __syncthreads();

        bf16x8 a[2], b[4];
#pragma unroll
        for (int mi = 0; mi < 2; ++mi)
            a[mi] = *(const bf16x8*)(&XS[16 * mi + l15][k0 + 8 * kg]);
#pragma unroll
        for (int ni = 0; ni < 4; ++ni)
            b[ni] = *(const bf16x8*)(&WS[jw + 16 * ni + l15][8 * kg]);
#pragma unroll
        for (int mi = 0; mi < 2; ++mi)
#pragma unroll
            for (int ni = 0; ni < 4; ++ni)
                acc[mi][ni] = __builtin_amdgcn_mfma_f32_16x16x32_bf16(a[mi], b[ni], acc[mi][ni], 0, 0, 0);
    }

    float ssq = 0.0f;
    float colp[4] = {0.0f, 0.0f, 0.0f, 0.0f};

    if (sel == 0) {
#pragma unroll
        for (int mi = 0; mi < 2; ++mi)
#pragma unroll
            for (int ni = 0; ni < 4; ++ni) {
                const int col = jw + 16 * ni + l15;
                const float bias = B[col];
#pragma unroll
                for (int r = 0; r < 4; ++r) {
                    const int row = i0 + 16 * mi + 4 * kg + r;
                    float val = acc[mi][ni][r] + bias;
                    QbG[(size_t)(row + 1) * 256 + col] = f2bf(val);
                    ssq = fmaf(val, val, ssq);
                }
            }
    } else if (sel == 1) {
#pragma unroll
        for (int mi = 0; mi < 2; ++mi)
#pragma unroll
            for (int ni = 0; ni < 4; ++ni) {
                const int col = jw + 16 * ni + l15;   // d
                const float bias = B[col];
                const int tb = i0 + 16 * mi + 4 * kg;
                bf16x4 pk;
#pragma unroll
                for (int r = 0; r < 4; ++r) {
                    float val = acc[mi][ni][r] + bias;
                    ssq = fmaf(val, val, ssq);
                    pk[r] = (short)f2bf(val);
                }
                *(bf16x4*)(KT + (size_t)col * 8192 + tb) = pk;
            }
    } else {
#pragma unroll
        for (int mi = 0; mi < 2; ++mi)
#pragma unroll
            for (int ni = 0; ni < 4; ++ni) {
                const int col = jw + 16 * ni + l15;   // j
                const float bias = B[col];
                const int tb = i0 + 16 * mi + 4 * kg;
                float v0 = acc[mi][ni][0] + bias, v1 = acc[mi][ni][1] + bias;
                float v2 = acc[mi][ni][2] + bias, v3 = acc[mi][ni][3] + bias;
                colp[ni] += v0 + v1 + v2 + v3;
                ushort_t* p = VT + (size_t)col * VT_S + tb + 1;
                p[0] = f2bf(v0);
                *(uint_t*)(p + 1) = (uint_t)f2bf(v1) | ((uint_t)f2bf(v2) << 16);
                p[3] = f2bf(v3);
            }
    }

    if (sel < 2) {
        float s = ssq;
#pragma unroll
        for (int o = 32; o > 0; o >>= 1) s += __shfl_down(s, o);
        if (lane == 0) lds4[wid] = s;
        __syncthreads();
        if (tid == 0)
            RED[sel * 256 + blockIdx.x] = lds4[0] + lds4[1] + lds4[2] + lds4[3];
    } else {
#pragma unroll
        for (int ni = 0; ni < 4; ++ni) {
            float v = colp[ni];
            v += __shfl_xor(v, 16);
            v += __shfl_xor(v, 32);
            if (kg == 0)
                SVP[(size_t)blockIdx.x * 256 + jw + 16 * ni + l15] = v;
        }
    }
}

// ---------------------------------------------------------------------------
// G_v[d][j] = sum_t K[t][d] * V[t+1-v][j].  grid (4, 4, 16) = 256 blocks.
// Direct-load version (identical to the 105 µs run).
// ---------------------------------------------------------------------------
__global__ void __launch_bounds__(256)
g_mfma(const ushort_t* __restrict__ KT, const ushort_t* __restrict__ VT,
       float* __restrict__ GP)
{
    const int tid = threadIdx.x, lane = tid & 63, wid = tid >> 6;
    const int d0 = blockIdx.x * 64;
    const int jw = blockIdx.y * 64 + wid * 16;
    const int ks = blockIdx.z;
    const int l15 = lane & 15, kg = lane >> 4;

    f32x4 acc[3][4];
#pragma unroll
    for (int v = 0; v < 3; ++v)
#pragma unroll
        for (int mi = 0; mi < 4; ++mi) acc[v][mi] = 0.0f;

    for (int tt = 0; tt < 512; tt += 32) {
        const int t0 = ks * 512 + tt;
        bf16x8 a[4];
#pragma unroll
        for (int mi = 0; mi < 4; ++mi)
            a[mi] = *(const bf16x8*)(KT + (size_t)(d0 + 16 * mi + l15) * 8192 + t0 + 8 * kg);

        const ushort_t* vp = VT + (size_t)(jw + l15) * VT_S + t0 + 8 * kg;
        uint4 r0 = *(const uint4*)vp;          // cols +0..7 -> v=2
        uint4 r2 = *(const uint4*)(vp + 2);    // cols +2..9 -> v=0
        uint4 m1;
        m1.x = (r0.x >> 16) | (r2.x << 16);
        m1.y = (r0.y >> 16) | (r2.y << 16);
        m1.z = (r0.z >> 16) | (r2.z << 16);
        m1.w = (r0.w >> 16) | (r2.w << 16);    // cols +1..8 -> v=1
        bf16x8 b2 = __builtin_bit_cast(bf16x8, r0);
        bf16x8 b0 = __builtin_bit_cast(bf16x8, r2);
        bf16x8 b1 = __builtin_bit_cast(bf16x8, m1);
#pragma unroll
        for (int mi = 0; mi < 4; ++mi) {
            acc[0][mi] = __builtin_amdgcn_mfma_f32_16x16x32_bf16(a[mi], b0, acc[0][mi], 0, 0, 0);
            acc[1][mi] = __builtin_amdgcn_mfma_f32_16x16x32_bf16(a[mi], b1, acc[1][mi], 0, 0, 0);
            acc[2][mi] = __builtin_amdgcn_mfma_f32_16x16x32_bf16(a[mi], b2, acc[2][mi], 0, 0, 0);
        }
    }

#pragma unroll
    for (int v = 0; v < 3; ++v) {
        float* gp = GP + (size_t)(ks * 3 + v) * 65536;
#pragma unroll
        for (int mi = 0; mi < 4; ++mi)
#pragma unroll
            for (int r = 0; r < 4; ++r)
                gp[(size_t)(d0 + 16 * mi + 4 * kg + r) * 256 + (jw + l15)]
                    = acc[v][mi][r];
    }
}

// ---------------------------------------------------------------------------
// MT[u][j][d] = scale * sum_v cw[u][v] * sum_ks GP[ks*3+v][d][j]  (bf16).
// scale via parallel 256-thread reduction; block 0 computes SVC.
// ---------------------------------------------------------------------------
__global__ void combine_m(const float* __restrict__ GP, const float* __restrict__ cw,
                          const float* __restrict__ RED, const float* __restrict__ SVP,
                          const float* __restrict__ cb,
                          ushort_t* __restrict__ MT, float* __restrict__ SVC)
{
    __shared__ float lds8[8];
    __shared__ float scsh;
    const int d = blockIdx.x, j = threadIdx.x;

    float sq = RED[j], sk = RED[256 + j];
#pragma unroll
    for (int o = 32; o > 0; o >>= 1) { sq += __shfl_down(sq, o); sk += __shfl_down(sk, o); }
    if ((j & 63) == 0) { lds8[j >> 6] = sq; lds8[4 + (j >> 6)] = sk; }

    float g[3] = {0.0f, 0.0f, 0.0f};
    for (int ks = 0; ks < 16; ++ks)
#pragma unroll
        for (int v = 0; v < 3; ++v)
            g[v] += GP[(size_t)(ks * 3 + v) * 65536 + (size_t)d * 256 + j];

    __syncthreads();
    if (j == 0) {
        float SQ = lds8[0] + lds8[1] + lds8[2] + lds8[3];
        float SK = lds8[4] + lds8[5] + lds8[6] + lds8[7];
        scsh = rsqrtf(SQ) * rsqrtf(SK);
    }
    __syncthreads();
    const float sc = scsh;

#pragma unroll
    for (int u = 0; u < 3; ++u) {
        float m = sc * (cw[u * 3 + 0] * g[0] + cw[u * 3 + 1] * g[1] + cw[u * 3 + 2] * g[2]);
        MT[(size_t)u * 65536 + (size_t)j * 256 + d] = f2bf(m);
    }
    if (d == 0) {
        float s = 0.0f;
        for (int b = 0; b < 256; ++b) s += SVP[(size_t)b * 256 + j];
        SVC[j] = cb[0] * s;
    }
}

// ---------------------------------------------------------------------------
// attn + LN + z fused. grid 256: block = 32 full rows; 4 waves each 64 cols.
// 1) attn[i][j] = sum_u sum_d Q[i+u-1][d] MT_u[j][d] + SVC[j] -> OUT (LDS)
// 2) wave-per-row LN: h = x + LN1(attn) -> d_out; l2 = LN2(h) -> OUT (reuse)
// 3) z = l2 @ m1w^T from LDS (m1w chunks staged bf16) -> Z + ZSP partials.
// ---------------------------------------------------------------------------
__global__ void __launch_bounds__(256)
attn_ln_z_mfma(const ushort_t* __restrict__ QbG, const ushort_t* __restrict__ MT,
               const float* __restrict__ SVC, const float* __restrict__ x,
               const float* __restrict__ ln1g, const float* __restrict__ ln1b,
               const float* __restrict__ ln2g, const float* __restrict__ ln2b,
               const float* __restrict__ m1w,
               float* __restrict__ h, float* __restrict__ Z,
               float* __restrict__ ZSP)
{
    __shared__ float OUT[32][260];          // attn, then l2 (f32); stride 260 -> 16B-aligned rows
    __shared__ ushort_t WS[128][40];        // m1w k-chunk (bf16)
    const int tid = threadIdx.x, lane = tid & 63, wid = tid >> 6;
    const int i0 = blockIdx.x * 32;
    const int jw = wid * 64;
    const int l15 = lane & 15, kg = lane >> 4;

    // ---- 1) attention GEMM (identical math/access to 105 µs version) ----
    f32x4 acc[2][4];
#pragma unroll
    for (int mi = 0; mi < 2; ++mi)
#pragma unroll
        for (int ni = 0; ni < 4; ++ni) acc[mi][ni] = 0.0f;

    for (int k0 = 0; k0 < 256; k0 += 32) {
        bf16x8 a[3][2], b[3][4];
#pragma unroll
        for (int u = 0; u < 3; ++u)
#pragma unroll
            for (int mi = 0; mi < 2; ++mi)
                a[u][mi] = *(const bf16x8*)(QbG
                    + (size_t)(i0 + 16 * mi + l15 + u) * 256 + k0 + 8 * kg);
#pragma unroll
        for (int u = 0; u < 3; ++u)
#pragma unroll
            for (int ni = 0; ni < 4; ++ni)
                b[u][ni] = *(const bf16x8*)(MT + (size_t)u * 65536
                    + (size_t)(jw + 16 * ni + l15) * 256 + k0 + 8 * kg);
#pragma unroll
        for (int mi = 0; mi < 2; ++mi)
#pragma unroll
            for (int ni = 0; ni < 4; ++ni)
#pragma unroll
                for (int u = 0; u < 3; ++u)
                    acc[mi][ni] = __builtin_amdgcn_mfma_f32_16x16x32_bf16(
                        a[u][mi], b[u][ni], acc[mi][ni], 0, 0, 0);
    }

#pragma unroll
    for (int mi = 0; mi < 2; ++mi)
#pragma unroll
        for (int ni = 0; ni < 4; ++ni) {
            const int col = jw + 16 * ni + l15;
            const float sv = SVC[col];
#pragma unroll
            for (int r = 0; r < 4; ++r)
                OUT[16 * mi + 4 * kg + r][col] = acc[mi][ni][r] + sv;
        }
    __syncthreads();

    // ---- 2) LN (wave-per-row, proven): h -> global, l2 -> OUT ----
    const float4 g14 = *(const float4*)(ln1g + lane * 4);
    const float4 b14 = *(const float4*)(ln1b + lane * 4);
    const float4 g24 = *(const float4*)(ln2g + lane * 4);
    const float4 b24 = *(const float4*)(ln2b + lane * 4);
#pragma unroll
    for (int rr = 0; rr < 8; ++rr) {
        const int row_l = wid * 8 + rr;
        const size_t off = (size_t)(i0 + row_l) * 256 + lane * 4;

        float4 a4 = *(const float4*)&OUT[row_l][lane * 4];
        float m = waveSum(a4.x + a4.y + a4.z + a4.w) * (1.0f / D_);
        float4 d4 = make_float4(a4.x - m, a4.y - m, a4.z - m, a4.w - m);
        float var = waveSum(d4.x * d4.x + d4.y * d4.y + d4.z * d4.z + d4.w * d4.w) * (1.0f / D_);
        float rs = rsqrtf(var + EPSF);

        float4 x4 = *(const float4*)(x + off);
        float4 h4;
        h4.x = x4.x + d4.x * rs * g14.x + b14.x;
        h4.y = x4.y + d4.y * rs * g14.y + b14.y;
        h4.z = x4.z + d4.z * rs * g14.z + b14.z;
        h4.w = x4.w + d4.w * rs * g14.w + b14.w;
        *(float4*)(h + off) = h4;

        float m2 = waveSum(h4.x + h4.y + h4.z + h4.w) * (1.0f / D_);
        float4 e4 = make_float4(h4.x - m2, h4.y - m2, h4.z - m2, h4.w - m2);
        float v2 = waveSum(e4.x * e4.x + e4.y * e4.y + e4.z * e4.z + e4.w * e4.w) * (1.0f / D_);
        float rs2 = rsqrtf(v2 + EPSF);

        float4 o4;
        o4.x = e4.x * rs2 * g24.x + b24.x;
        o4.y = e4.y * rs2 * g24.y + b24.y;
        o4.z = e4.z * rs2 * g24.z + b24.z;
        o4.w = e4.w * rs2 * g24.w + b24.w;
        *(float4*)&OUT[row_l][lane * 4] = o4;   // l2 stays in LDS
    }
    __syncthreads();

    // ---- 3) z = l2 @ m1w^T from LDS; 4 waves each own 32 of 128 cols ----
    const int jz = wid * 32;
    f32x4 zacc[2][2];
#pragma unroll
    for (int mi = 0; mi < 2; ++mi) { zacc[mi][0] = 0.0f; zacc[mi][1] = 0.0f; }

    for (int k0 = 0; k0 < 256; k0 += 32) {
        if (k0) __syncthreads();   // prior chunk's WS reads done
#pragma unroll
        for (int p = 0; p < 2; ++p) {
            int idx = p * 256 + tid;
            int j  = idx >> 2;
            int c8 = (idx & 3) * 8;
            const float* wp = m1w + (size_t)j * 256 + k0 + c8;
            *(bf16x8*)(&WS[j][c8]) = cvt8(*(const float4*)wp, *(const float4*)(wp + 4));
        }
        __syncthreads();

        bf16x8 a[2], b[2];
#pragma unroll
        for (int mi = 0; mi < 2; ++mi) {
            const float* lp = &OUT[16 * mi + l15][k0 + 8 * kg];
            a[mi] = cvt8(*(const float4*)lp, *(const float4*)(lp + 4));
        }
#pragma unroll
        for (int ni = 0; ni < 2; ++ni)
            b[ni] = *(const bf16x8*)(&WS[jz + 16 * ni + l15][8 * kg]);
#pragma unroll
        for (int mi = 0; mi < 2; ++mi)
#pragma unroll
            for (int ni = 0; ni < 2; ++ni)
                zacc[mi][ni] = __builtin_amdgcn_mfma_f32_16x16x32_bf16(a[mi], b[ni], zacc[mi][ni], 0, 0, 0);
    }

    float s[2] = {0.0f, 0.0f}, q[2] = {0.0f, 0.0f};
#pragma unroll
    for (int mi = 0; mi < 2; ++mi)
#pragma unroll
        for (int ni = 0; ni < 2; ++ni) {
            const int col = jz + 16 * ni + l15;
#pragma unroll
            for (int r = 0; r < 4; ++r) {
                float zv = zacc[mi][ni][r];
                Z[(size_t)(i0 + 16 * mi + 4 * kg + r) * 128 + col] = zv;
                s[ni] += zv;
                q[ni] = fmaf(zv, zv, q[ni]);
            }
        }
#pragma unroll
    for (int ni = 0; ni < 2; ++ni) {
        s[ni] += __shfl_xor(s[ni], 16); s[ni] += __shfl_xor(s[ni], 32);
        q[ni] += __shfl_xor(q[ni], 16); q[ni] += __shfl_xor(q[ni], 32);
        if (kg == 0) {
            ZSP[(size_t)blockIdx.x * 256 + jz + 16 * ni + l15] = s[ni];
            ZSP[(size_t)blockIdx.x * 256 + 128 + jz + 16 * ni + l15] = q[ni];
        }
    }
}

// ---------------------------------------------------------------------------
// out = h + relu(z*a+b) @ m2w^T via MFMA, direct loads (105 µs version).
// grid 256: 32 rows x 256 cols, 4 waves each 64 cols. BN affine from ZSP.
// ---------------------------------------------------------------------------
__global__ void __launch_bounds__(256)
gemm_out_mfma(const float* __restrict__ Z, const float* __restrict__ W,
              const float* __restrict__ ZSP,
              const float* __restrict__ bng, const float* __restrict__ bnb,
              float* out)
{
    __shared__ float bnA[128], bnB[128];
    const int tid = threadIdx.x, lane = tid & 63, wid = tid >> 6;
    const int i0 = blockIdx.x * 32;
    const int jw = wid * 64;
    const int l15 = lane & 15, kg = lane >> 4;

    if (tid < 128) {
        float s = 0.0f, q = 0.0f;
        for (int b = 0; b < 256; ++b) {
            s += ZSP[(size_t)b * 256 + tid];
            q += ZSP[(size_t)b * 256 + 128 + tid];
        }
        float mu = s * (1.0f / N_);
        float var = q * (1.0f / N_) - mu * mu;
        float aa = rsqrtf(var + EPSF) * bng[tid];
        bnA[tid] = aa;
        bnB[tid] = bnb[tid] - mu * aa;
    }
    __syncthreads();

    f32x4 acc[2][4];
#pragma unroll
    for (int mi = 0; mi < 2; ++mi)
#pragma unroll
        for (int ni = 0; ni < 4; ++ni) acc[mi][ni] = 0.0f;

    for (int k0 = 0; k0 < 128; k0 += 32) {
        float ba[8], bb[8];
#pragma unroll
        for (int e = 0; e < 8; ++e) {
            ba[e] = bnA[k0 + 8 * kg + e];
            bb[e] = bnB[k0 + 8 * kg + e];
        }
        bf16x8 a[2], b[4];
#pragma unroll
        for (int mi = 0; mi < 2; ++mi) {
            const float* p = Z + (size_t)(i0 + 16 * mi + l15) * 128 + k0 + 8 * kg;
            float4 f0 = *(const float4*)p;
            float4 f1 = *(const float4*)(p + 4);
            float4 g0, g1;
            g0.x = fmaxf(fmaf(f0.x, ba[0], bb[0]), 0.0f);
            g0.y = fmaxf(fmaf(f0.y, ba[1], bb[1]), 0.0f);
            g0.z = fmaxf(fmaf(f0.z, ba[2], bb[2]), 0.0f);
            g0.w = fmaxf(fmaf(f0.w, ba[3], bb[3]), 0.0f);
            g1.x = fmaxf(fmaf(f1.x, ba[4], bb[4]), 0.0f);
            g1.y = fmaxf(fmaf(f1.y, ba[5], bb[5]), 0.0f);
            g1.z = fmaxf(fmaf(f1.z, ba[6], bb[6]), 0.0f);
            g1.w = fmaxf(fmaf(f1.w, ba[7], bb[7]), 0.0f);
            a[mi] = cvt8(g0, g1);
        }
#pragma unroll
        for (int ni = 0; ni < 4; ++ni) {
            const float* p = W + (size_t)(jw + 16 * ni + l15) * 128 + k0 + 8 * kg;
            b[ni] = cvt8(*(const float4*)p, *(const float4*)(p + 4));
        }
#pragma unroll
        for (int mi = 0; mi < 2; ++mi)
#pragma unroll
            for (int ni = 0; ni < 4; ++ni)
                acc[mi][ni] = __builtin_amdgcn_mfma_f32_16x16x32_bf16(a[mi], b[ni], acc[mi][ni], 0, 0, 0);
    }

#pragma unroll
    for (int mi = 0; mi < 2; ++mi)
#pragma unroll
        for (int ni = 0; ni < 4; ++ni)
#pragma unroll
            for (int r = 0; r < 4; ++r) {
                const size_t idx = (size_t)(i0 + 16 * mi + 4 * kg + r) * 256
                                 + (jw + 16 * ni + l15);
                out[idx] = out[idx] + acc[mi][ni][r];
            }
}

// ---------------------------------------------------------------------------
extern "C" void kernel_launch(void* const* d_in, const int* in_sizes, int n_in,
                              void* d_out, int out_size, void* d_ws, size_t ws_size,
                              hipStream_t stream)
{
    const float* x    = (const float*)d_in[0];
    const float* wq   = (const float*)d_in[1];
    const float* bq   = (const float*)d_in[2];
    const float* wk   = (const float*)d_in[3];
    const float* bk   = (const float*)d_in[4];
    const float* wv   = (const float*)d_in[5];
    const float* bv   = (const float*)d_in[6];
    const float* cw   = (const float*)d_in[7];
    const float* cb   = (const float*)d_in[8];
    const float* m1w  = (const float*)d_in[9];
    const float* m2w  = (const float*)d_in[10];
    const float* bng  = (const float*)d_in[11];
    const float* bnb  = (const float*)d_in[12];
    const float* ln1g = (const float*)d_in[13];
    const float* ln1b = (const float*)d_in[14];
    const float* ln2g = (const float*)d_in[15];
    const float* ln2b = (const float*)d_in[16];

    float* outF = (float*)d_out;
    char*  wsb  = (char*)d_ws;
    if (ws_size < WS_NEED) return;

    ushort_t* QbG = (ushort_t*)(wsb + OFF_QB);
    ushort_t* KT  = (ushort_t*)(wsb + OFF_KT);
    ushort_t* VT  = (ushort_t*)(wsb + OFF_VT);
    float*    GP  = (float*)(wsb + OFF_GP);
    ushort_t* MT  = (ushort_t*)(wsb + OFF_MT);
    float*    SVP = (float*)(wsb + OFF_SVP);
    float*    SVC = (float*)(wsb + OFF_SVC);
    float*    RED = (float*)(wsb + OFF_RED);
    float*    ZSP = (float*)(wsb + OFF_ZSP);
    float*    Z   = (float*)(wsb + OFF_GP);   // GP dead after combine_m

    const dim3 b256(256);

    qkv_mfma<<<dim3(256, 3), b256, 0, stream>>>(x, wq, bq, wk, bk, wv, bv,
                                                QbG, KT, VT, RED, SVP);
    g_mfma<<<dim3(4, 4, 16), b256, 0, stream>>>(KT, VT, GP);
    combine_m<<<256, b256, 0, stream>>>(GP, cw, RED, SVP, cb, MT, SVC);
    attn_ln_z_mfma<<<256, b256, 0, stream>>>(QbG, MT, SVC, x,
                                             ln1g, ln1b, ln2g, ln2b, m1w,
                                             outF, Z, ZSP);
    gemm_out_mfma<<<256, b256, 0, stream>>>(Z, m2w, ZSP, bng, bnb, outF);
}